// Round 2
// 1278.353 us; speedup vs baseline: 2.1992x; 2.1992x over previous
//
#include <hip/hip_runtime.h>
#include <hip/hip_bf16.h>
#include <cstdint>

#define TT   2048
#define CC   1024
#define NHH  16
#define HDD  64
#define EE   8
#define HIDD 4096
#define ROWCAP 5120   // 4096 token-expert rows + 8*128 padding, multiple of 128
#define EPSF 1e-6f

typedef __attribute__((ext_vector_type(8))) short  s16x8;
typedef __attribute__((ext_vector_type(4))) float  f32x4;

static __device__ __forceinline__ unsigned short f2bf(float f) {
    union { float f; unsigned u; } a; a.f = f;
    unsigned r = a.u + 0x7FFFu + ((a.u >> 16) & 1u);   // RNE
    return (unsigned short)(r >> 16);
}
static __device__ __forceinline__ float bf2f(unsigned short s) {
    union { unsigned u; float f; } a; a.u = ((unsigned)s) << 16;
    return a.f;
}
static __device__ __forceinline__ void split_bf(float f, unsigned short& hi,
                                                unsigned short& lo) {
    hi = f2bf(f);
    lo = f2bf(f - bf2f(hi));
}

// ---------------------------------------------------------------------------
__global__ void init_kernel(int* rowtok, int* cnt, float* psum, float* argc) {
    int g = blockIdx.x * 256 + threadIdx.x;
    if (g < ROWCAP) rowtok[g] = -1;
    if (g < EE) { cnt[g] = 0; psum[g] = 0.f; argc[g] = 0.f; }
}

// ---------------------------------------------------------------------------
__global__ void rmsnorm_kernel(const float* __restrict__ x,
                               const float* __restrict__ w,
                               float* __restrict__ outf,
                               unsigned short* __restrict__ outb) {
    int t = blockIdx.x, tid = threadIdx.x;
    __shared__ float red[256];
    const float* xr = x + (size_t)t * CC;
    float ss = 0.f;
    for (int c = tid; c < CC; c += 256) { float v = xr[c]; ss += v * v; }
    red[tid] = ss; __syncthreads();
    for (int s = 128; s > 0; s >>= 1) {
        if (tid < s) red[tid] += red[tid + s];
        __syncthreads();
    }
    float inv = rsqrtf(red[0] * (1.0f / CC) + EPSF);
    for (int c = tid; c < CC; c += 256) {
        float v = xr[c] * inv * w[c];
        if (outf) outf[(size_t)t * CC + c] = v;
        if (outb) outb[(size_t)t * CC + c] = f2bf(v);
    }
}

// ---------------------------------------------------------------------------
// Near-fp32 MFMA GEMM via split-bf16 (hi+lo), 128x128 tile, BK=32, 4 waves.
// A fp32 [rows x K], B fp32 [K x N] (transposed+split into LDS). N==1024.
// MODE 0: fused QKV (blockIdx.y: 0-7 wq, 8-15 wk, 16-23 wv)
// MODE 1: proj, O0 = acc + res
template<int MODE>
__global__ __launch_bounds__(256)
void gemm_precise(const float* __restrict__ A,
                  const float* __restrict__ B0, const float* __restrict__ B1,
                  const float* __restrict__ B2,
                  float* __restrict__ O0, float* __restrict__ O1,
                  float* __restrict__ O2,
                  const float* __restrict__ res, int K) {
    const int N = 1024;
    int row0 = blockIdx.x * 128;
    int n0; const float* Bp; int mat = 0;
    if (MODE == 0) {
        mat = blockIdx.y >> 3;
        n0 = (blockIdx.y & 7) * 128;
        Bp = (mat == 0) ? B0 : (mat == 1 ? B1 : B2);
    } else {
        n0 = blockIdx.y * 128;
        Bp = B0;
    }

    __shared__ unsigned short AsH[128 * 40], AsL[128 * 40];
    __shared__ unsigned short BsH[128 * 40], BsL[128 * 40];

    int tid = threadIdx.x, lane = tid & 63, wave = tid >> 6;
    int wm = (wave & 1) * 64, wn = (wave >> 1) * 64;
    int l15 = lane & 15, q4 = lane >> 4;
    const unsigned short* aRdH = AsH + (wm + l15) * 40 + q4 * 8;
    const unsigned short* aRdL = AsL + (wm + l15) * 40 + q4 * 8;
    const unsigned short* bRdH = BsH + (wn + l15) * 40 + q4 * 8;
    const unsigned short* bRdL = BsL + (wn + l15) * 40 + q4 * 8;

    int am = tid & 127, aoff = (tid >> 7) * 16;
    int bn = tid & 127, bk2 = (tid >> 7) * 2;
    const float* arow = A + (size_t)(row0 + am) * K;
    const float* bcol = Bp + n0 + bn;
    int awr = am * 40 + aoff;

    f32x4 acc[4][4];
    const f32x4 z4 = {0.f, 0.f, 0.f, 0.f};
#pragma unroll
    for (int mi = 0; mi < 4; mi++)
#pragma unroll
        for (int ni = 0; ni < 4; ni++) acc[mi][ni] = z4;

    for (int k0 = 0; k0 < K; k0 += 32) {
        __syncthreads();
        // stage A: 16 fp32 -> hi/lo bf16
        float av[16];
        *(f32x4*)&av[0]  = *(const f32x4*)(arow + k0 + aoff);
        *(f32x4*)&av[4]  = *(const f32x4*)(arow + k0 + aoff + 4);
        *(f32x4*)&av[8]  = *(const f32x4*)(arow + k0 + aoff + 8);
        *(f32x4*)&av[12] = *(const f32x4*)(arow + k0 + aoff + 12);
        s16x8 h0, h1, l0, l1;
#pragma unroll
        for (int i = 0; i < 8; i++) {
            unsigned short h, l;
            split_bf(av[i], h, l); h0[i] = (short)h; l0[i] = (short)l;
            split_bf(av[i + 8], h, l); h1[i] = (short)h; l1[i] = (short)l;
        }
        *(s16x8*)(AsH + awr) = h0; *(s16x8*)(AsH + awr + 8) = h1;
        *(s16x8*)(AsL + awr) = l0; *(s16x8*)(AsL + awr + 8) = l1;
        // stage B: fp32 -> hi/lo bf16, transposed (Bs[n][k]), k-pairs b32
        const float* bc = bcol + (size_t)k0 * N;
#pragma unroll
        for (int it = 0; it < 8; it++) {
            int k = it * 4 + bk2;
            float v0 = bc[(size_t)k * N];
            float v1 = bc[(size_t)(k + 1) * N];
            unsigned short ha, la, hb, lb;
            split_bf(v0, ha, la); split_bf(v1, hb, lb);
            *(unsigned int*)(BsH + bn * 40 + k) =
                (unsigned int)ha | ((unsigned int)hb << 16);
            *(unsigned int*)(BsL + bn * 40 + k) =
                (unsigned int)la | ((unsigned int)lb << 16);
        }
        __syncthreads();
        s16x8 aH[4], aL[4], bH[4], bL[4];
#pragma unroll
        for (int mi = 0; mi < 4; mi++) {
            aH[mi] = *(const s16x8*)(aRdH + mi * 640);
            aL[mi] = *(const s16x8*)(aRdL + mi * 640);
        }
#pragma unroll
        for (int ni = 0; ni < 4; ni++) {
            bH[ni] = *(const s16x8*)(bRdH + ni * 640);
            bL[ni] = *(const s16x8*)(bRdL + ni * 640);
        }
#pragma unroll
        for (int mi = 0; mi < 4; mi++)
#pragma unroll
            for (int ni = 0; ni < 4; ni++) {
                acc[mi][ni] = __builtin_amdgcn_mfma_f32_16x16x32_bf16(
                    aH[mi], bH[ni], acc[mi][ni], 0, 0, 0);
                acc[mi][ni] = __builtin_amdgcn_mfma_f32_16x16x32_bf16(
                    aH[mi], bL[ni], acc[mi][ni], 0, 0, 0);
                acc[mi][ni] = __builtin_amdgcn_mfma_f32_16x16x32_bf16(
                    aL[mi], bH[ni], acc[mi][ni], 0, 0, 0);
                acc[mi][ni] = __builtin_amdgcn_mfma_f32_16x16x32_bf16(
                    aL[mi], bL[ni], acc[mi][ni], 0, 0, 0);
            }
    }

    // C/D layout: col=lane&15, row=(lane>>4)*4+reg  [m89-verified]
#pragma unroll
    for (int mi = 0; mi < 4; mi++)
#pragma unroll
        for (int r = 0; r < 4; r++) {
            int gm = row0 + wm + mi * 16 + q4 * 4 + r;
#pragma unroll
            for (int ni = 0; ni < 4; ni++) {
                int gn = n0 + wn + ni * 16 + l15;
                float v = acc[mi][ni][r];
                size_t idx = (size_t)gm * 1024 + gn;
                if (MODE == 0) {
                    float* Od = (mat == 0) ? O0 : (mat == 1 ? O1 : O2);
                    Od[idx] = v;
                } else {
                    O0[idx] = v + res[idx];
                }
            }
        }
}

// ---------------------------------------------------------------------------
// Fast bf16 MFMA GEMM for MoE (output-only path, tolerance-covered).
// MODE 2: MoE up, gathered A rows via rowtok, per-expert B, bf16 out
// MODE 3: MoE down, direct A rows, per-expert B, weighted atomicAdd into O0
template<int MODE>
__global__ __launch_bounds__(256)
void gemm_bf16(const unsigned short* __restrict__ A,
               const float* __restrict__ B0,
               float* __restrict__ O0, unsigned short* __restrict__ Obf,
               const int* __restrict__ offs, const int* __restrict__ rowtok,
               const float* __restrict__ roww, int K, int N) {
    int row0 = blockIdx.x * 128;
    int n0 = blockIdx.y * 128;
    int total = offs[EE];
    if (row0 >= total) return;
    int e = 0;
#pragma unroll
    for (int ee = 0; ee < EE; ee++) if (row0 >= offs[ee + 1]) e = ee + 1;
    const float* Bp = B0 + (size_t)e * K * N;

    __shared__ unsigned short As[128 * 40];
    __shared__ unsigned short Bs[128 * 40];

    int tid = threadIdx.x, lane = tid & 63, wave = tid >> 6;
    int wm = (wave & 1) * 64, wn = (wave >> 1) * 64;
    int l15 = lane & 15, q4 = lane >> 4;
    const unsigned short* aRd = As + (wm + l15) * 40 + q4 * 8;
    const unsigned short* bRd = Bs + (wn + l15) * 40 + q4 * 8;

    int am = tid & 127, aoff = (tid >> 7) * 16;
    int bn = tid & 127, bk2 = (tid >> 7) * 2;
    const unsigned short* arow;
    if (MODE == 2) {
        int tok = rowtok[row0 + am];
        arow = (tok >= 0) ? (A + (size_t)tok * K) : nullptr;
    } else {
        arow = A + (size_t)(row0 + am) * K;
    }
    unsigned short* aWr = As + am * 40 + aoff;
    const float* bcol = Bp + n0 + bn;

    f32x4 acc[4][4];
    const f32x4 z4 = {0.f, 0.f, 0.f, 0.f};
#pragma unroll
    for (int mi = 0; mi < 4; mi++)
#pragma unroll
        for (int ni = 0; ni < 4; ni++) acc[mi][ni] = z4;
    const s16x8 z8 = {0, 0, 0, 0, 0, 0, 0, 0};

    for (int k0 = 0; k0 < K; k0 += 32) {
        __syncthreads();
        s16x8 av0 = z8, av1 = z8;
        if (arow) {
            av0 = *(const s16x8*)(arow + k0 + aoff);
            av1 = *(const s16x8*)(arow + k0 + aoff + 8);
        }
        *(s16x8*)aWr = av0;
        *(s16x8*)(aWr + 8) = av1;
        const float* bc = bcol + (size_t)k0 * N;
#pragma unroll
        for (int it = 0; it < 8; it++) {
            int k = it * 4 + bk2;
            float v0 = bc[(size_t)k * N];
            float v1 = bc[(size_t)(k + 1) * N];
            *(unsigned int*)(Bs + bn * 40 + k) =
                (unsigned int)f2bf(v0) | ((unsigned int)f2bf(v1) << 16);
        }
        __syncthreads();
        s16x8 af[4], bfr[4];
#pragma unroll
        for (int mi = 0; mi < 4; mi++) af[mi] = *(const s16x8*)(aRd + mi * 640);
#pragma unroll
        for (int ni = 0; ni < 4; ni++) bfr[ni] = *(const s16x8*)(bRd + ni * 640);
#pragma unroll
        for (int mi = 0; mi < 4; mi++)
#pragma unroll
            for (int ni = 0; ni < 4; ni++)
                acc[mi][ni] = __builtin_amdgcn_mfma_f32_16x16x32_bf16(
                    af[mi], bfr[ni], acc[mi][ni], 0, 0, 0);
    }

#pragma unroll
    for (int mi = 0; mi < 4; mi++)
#pragma unroll
        for (int r = 0; r < 4; r++) {
            int gm = row0 + wm + mi * 16 + q4 * 4 + r;
            int tok = 0; float wgt = 0.f;
            if (MODE == 3) {
                tok = rowtok[gm];
                if (tok < 0) continue;
                wgt = roww[gm];
            }
#pragma unroll
            for (int ni = 0; ni < 4; ni++) {
                int gn = n0 + wn + ni * 16 + l15;
                float v = acc[mi][ni][r];
                if (MODE == 2) {
                    Obf[(size_t)gm * 4096 + gn] = f2bf(v);
                } else {
                    atomicAdd(&O0[(size_t)tok * 1024 + gn], wgt * v);
                }
            }
        }
}

// ---------------------------------------------------------------------------
__global__ void rope_kernel(float* buf) {
    int lane = threadIdx.x;
    int fh = blockIdx.x * 2 + (lane >> 5);
    int i = lane & 31;
    int t = fh >> 4;
    size_t base = (size_t)fh * HDD;
    float v0 = buf[base + 2 * i];
    float v1 = buf[base + 2 * i + 1];
    float freq = powf(10000.f, -(float)i / 32.f);
    float ang = (float)t * freq;
    float sn, cs;
    sincosf(ang, &sn, &cs);
    buf[base + i]      = v0 * cs - v1 * sn;
    buf[base + 32 + i] = v0 * sn + v1 * cs;
}

// ---------------------------------------------------------------------------
// Flash attention, near-fp32 MFMA path.
// Grid: 512 wgs = 16 heads x 32 q-tiles of 64 rows, 4 waves/wg, 16 q-rows/wave.
// Balance remap: co-resident wgs get q-tiles i and 31-i (causal imbalance).
// QK^T: split-bf16 hi/lo Q,K, 3-term MFMA  (score err ~1e-6).
// PV:   split-bf16 hi/lo P,V, 3-term MFMA  (y err ~5e-6).
// Near-fp32 everywhere so router top-2 decisions match the fp32 reference
// (plain-bf16 PV perturbs expert logits ~1e-4 -> expert flips -> absmax ~0.8).
__global__ __launch_bounds__(256)
void attn_flash(const float* __restrict__ q, const float* __restrict__ k,
                const float* __restrict__ v, float* __restrict__ y) {
    int g = blockIdx.x;
    int h = g & 15;
    int gg = g >> 4;                       // 0..31
    int tile = (gg < 16) ? gg : 47 - gg;   // pairs tiles i with 31-i across CU rounds
    int q0 = tile * 64;

    int tid = threadIdx.x;
    int lane = tid & 63, wave = tid >> 6;
    int l15 = lane & 15, q4 = lane >> 4;

    __shared__ unsigned short KsH[64 * 72];   // K hi  [kv][d], pad 8
    __shared__ unsigned short KsL[64 * 72];   // K lo
    __shared__ unsigned short VsH[64 * 72];   // V^T hi [d][kv]
    __shared__ unsigned short VsL[64 * 72];   // V^T lo
    __shared__ unsigned short PsH[4][16 * 72]; // per-wave P hi [q_local][kv]
    __shared__ unsigned short PsL[4][16 * 72]; // per-wave P lo

    // Q fragments in registers (A-layout: row=l15, k = s*32 + q4*8 + i)
    s16x8 qh[2], ql[2];
    {
        const float* qr = q + (size_t)(q0 + wave * 16 + l15) * CC + h * HDD;
#pragma unroll
        for (int s = 0; s < 2; s++) {
            int d0 = s * 32 + q4 * 8;
            f32x4 a0 = *(const f32x4*)(qr + d0);
            f32x4 a1 = *(const f32x4*)(qr + d0 + 4);
#pragma unroll
            for (int i = 0; i < 4; i++) {
                unsigned short hh, ll;
                split_bf(a0[i], hh, ll); qh[s][i] = (short)hh; ql[s][i] = (short)ll;
                split_bf(a1[i], hh, ll); qh[s][i + 4] = (short)hh; ql[s][i + 4] = (short)ll;
            }
        }
    }

    f32x4 O[4];
    const f32x4 z4 = {0.f, 0.f, 0.f, 0.f};
#pragma unroll
    for (int n = 0; n < 4; n++) O[n] = z4;
    float mrow[4] = {-1e30f, -1e30f, -1e30f, -1e30f};
    float lrow[4] = {0.f, 0.f, 0.f, 0.f};

    int nblk = tile + 1;
    int qrow0 = q0 + wave * 16 + q4 * 4;   // this lane's base q-row

    for (int jb = 0; jb < nblk; jb++) {
        int j0 = jb * 64;
        __syncthreads();   // all waves done reading previous K/V
        {
            // stage K (hi/lo) and V^T (hi/lo): thread t -> kv = t>>2, d-chunk (t&3)*16
            int kv = tid >> 2, dc = (tid & 3) * 16;
            const float* kr = k + (size_t)(j0 + kv) * CC + h * HDD + dc;
            const float* vr = v + (size_t)(j0 + kv) * CC + h * HDD + dc;
#pragma unroll
            for (int i = 0; i < 16; i += 4) {
                f32x4 kq = *(const f32x4*)(kr + i);
                f32x4 vq = *(const f32x4*)(vr + i);
#pragma unroll
                for (int u = 0; u < 4; u++) {
                    unsigned short hh, ll;
                    split_bf(kq[u], hh, ll);
                    KsH[kv * 72 + dc + i + u] = hh;
                    KsL[kv * 72 + dc + i + u] = ll;
                    split_bf(vq[u], hh, ll);
                    VsH[(dc + i + u) * 72 + kv] = hh;
                    VsL[(dc + i + u) * 72 + kv] = ll;
                }
            }
        }
        __syncthreads();   // staged data visible

        // S = Q K^T  (3-term split: qh*kh + ql*kh + qh*kl)
        f32x4 S[4];
#pragma unroll
        for (int n = 0; n < 4; n++) S[n] = z4;
#pragma unroll
        for (int s = 0; s < 2; s++) {
#pragma unroll
            for (int n = 0; n < 4; n++) {
                const unsigned short* kb = KsH + (n * 16 + l15) * 72 + s * 32 + q4 * 8;
                const unsigned short* kl = KsL + (n * 16 + l15) * 72 + s * 32 + q4 * 8;
                s16x8 bh = *(const s16x8*)kb;
                s16x8 bl = *(const s16x8*)kl;
                S[n] = __builtin_amdgcn_mfma_f32_16x16x32_bf16(qh[s], bh, S[n], 0, 0, 0);
                S[n] = __builtin_amdgcn_mfma_f32_16x16x32_bf16(ql[s], bh, S[n], 0, 0, 0);
                S[n] = __builtin_amdgcn_mfma_f32_16x16x32_bf16(qh[s], bl, S[n], 0, 0, 0);
            }
        }
#pragma unroll
        for (int n = 0; n < 4; n++) S[n] = S[n] * 0.125f;

        // causal mask only needed in the diagonal block
        if (jb == tile) {
#pragma unroll
            for (int n = 0; n < 4; n++) {
                int col = j0 + n * 16 + l15;
#pragma unroll
                for (int r = 0; r < 4; r++)
                    if (col > qrow0 + r) S[n][r] = -1e30f;
            }
        }

        // online softmax: row r lives in the 16 lanes with the same (lane>>4)
#pragma unroll
        for (int r = 0; r < 4; r++) {
            float mx = fmaxf(fmaxf(S[0][r], S[1][r]), fmaxf(S[2][r], S[3][r]));
            mx = fmaxf(mx, __shfl_xor(mx, 1));
            mx = fmaxf(mx, __shfl_xor(mx, 2));
            mx = fmaxf(mx, __shfl_xor(mx, 4));
            mx = fmaxf(mx, __shfl_xor(mx, 8));
            float mnew = fmaxf(mrow[r], mx);
            float corr = __expf(mrow[r] - mnew);
            mrow[r] = mnew;
            float rs = 0.f;
#pragma unroll
            for (int n = 0; n < 4; n++) {
                float p = __expf(S[n][r] - mnew);
                S[n][r] = p;
                rs += p;
            }
            rs += __shfl_xor(rs, 1);
            rs += __shfl_xor(rs, 2);
            rs += __shfl_xor(rs, 4);
            rs += __shfl_xor(rs, 8);
            lrow[r] = lrow[r] * corr + rs;
#pragma unroll
            for (int n = 0; n < 4; n++) O[n][r] *= corr;
        }

        // P (C/D layout) -> per-wave LDS hi/lo tiles -> A-layout fragments
#pragma unroll
        for (int n = 0; n < 4; n++)
#pragma unroll
            for (int r = 0; r < 4; r++) {
                unsigned short hh, ll;
                split_bf(S[n][r], hh, ll);
                PsH[wave][(q4 * 4 + r) * 72 + n * 16 + l15] = hh;
                PsL[wave][(q4 * 4 + r) * 72 + n * 16 + l15] = ll;
            }
        asm volatile("s_waitcnt lgkmcnt(0)" ::: "memory");
        __builtin_amdgcn_sched_barrier(0);

        // O += P V  (3-term split: ph*vh + pl*vh + ph*vl)
#pragma unroll
        for (int s = 0; s < 2; s++) {
            s16x8 ph = *(const s16x8*)(&PsH[wave][l15 * 72 + s * 32 + q4 * 8]);
            s16x8 pl = *(const s16x8*)(&PsL[wave][l15 * 72 + s * 32 + q4 * 8]);
#pragma unroll
            for (int n = 0; n < 4; n++) {
                s16x8 vh = *(const s16x8*)(VsH + (n * 16 + l15) * 72 + s * 32 + q4 * 8);
                s16x8 vl = *(const s16x8*)(VsL + (n * 16 + l15) * 72 + s * 32 + q4 * 8);
                O[n] = __builtin_amdgcn_mfma_f32_16x16x32_bf16(ph, vh, O[n], 0, 0, 0);
                O[n] = __builtin_amdgcn_mfma_f32_16x16x32_bf16(pl, vh, O[n], 0, 0, 0);
                O[n] = __builtin_amdgcn_mfma_f32_16x16x32_bf16(ph, vl, O[n], 0, 0, 0);
            }
        }
    }

    // finalize: y = O / l
#pragma unroll
    for (int r = 0; r < 4; r++) {
        float inv = 1.f / lrow[r];
        float* yr = y + (size_t)(qrow0 + r) * CC + h * HDD;
#pragma unroll
        for (int n = 0; n < 4; n++)
            yr[n * 16 + l15] = O[n][r] * inv;
    }
}

// ---------------------------------------------------------------------------
__global__ void router_kernel(const float* __restrict__ hn,
                              const float* __restrict__ rw,
                              int* topi, float* topp,
                              int* cnt, float* psum, float* argc) {
    int t = blockIdx.x, lane = threadIdx.x;
    float acc[EE] = {};
    const float* xr = hn + (size_t)t * CC;
    for (int c = lane; c < CC; c += 64) {
        float xv = xr[c];
        const float* rr = rw + (size_t)c * EE;
#pragma unroll
        for (int e = 0; e < EE; e++) acc[e] += xv * rr[e];
    }
#pragma unroll
    for (int e = 0; e < EE; e++)
        for (int off = 32; off > 0; off >>= 1) acc[e] += __shfl_down(acc[e], off);
    if (lane == 0) {
        float m = acc[0];
        for (int e = 1; e < EE; e++) m = fmaxf(m, acc[e]);
        float p[EE], s = 0.f;
        for (int e = 0; e < EE; e++) { p[e] = expf(acc[e] - m); s += p[e]; }
        for (int e = 0; e < EE; e++) p[e] /= s;
        int i0 = 0;
        for (int e = 1; e < EE; e++) if (p[e] > p[i0]) i0 = e;
        int i1 = (i0 == 0) ? 1 : 0;
        for (int e = 0; e < EE; e++) if (e != i0 && p[e] > p[i1]) i1 = e;
        float s2 = p[i0] + p[i1];
        topi[t * 2] = i0; topi[t * 2 + 1] = i1;
        topp[t * 2] = p[i0] / s2; topp[t * 2 + 1] = p[i1] / s2;
        atomicAdd(&cnt[i0], 1); atomicAdd(&cnt[i1], 1);
        atomicAdd(&argc[i0], 1.0f);
        for (int e = 0; e < EE; e++) atomicAdd(&psum[e], p[e]);
    }
}

// ---------------------------------------------------------------------------
// Per-expert padded offsets (128-aligned to match 128-row GEMM tiles).
__global__ void offsets_kernel(const int* cnt, int* offs, int* cursor,
                               const float* psum, const float* argc, float* out) {
    if (threadIdx.x == 0 && blockIdx.x == 0) {
        int o = 0;
        for (int e = 0; e < EE; e++) {
            offs[e] = o; cursor[e] = o;
            o += ((cnt[e] + 127) >> 7) << 7;
        }
        offs[EE] = o;
        float fp = 0.f;
        for (int e = 0; e < EE; e++)
            fp += (argc[e] * (1.f / TT)) * (psum[e] * (1.f / TT));
        out[(size_t)TT * CC] = 0.01f * (float)EE * fp;
    }
}

// ---------------------------------------------------------------------------
__global__ void scatter_kernel(const int* topi, const float* topp, int* cursor,
                               int* rowtok, float* roww) {
    int g = blockIdx.x * 256 + threadIdx.x;
    if (g >= TT * 2) return;
    int e = topi[g];
    int r = atomicAdd(&cursor[e], 1);
    rowtok[r] = g >> 1;
    roww[r] = topp[g];
}

// ---------------------------------------------------------------------------
__global__ void copy_kernel(const float* __restrict__ h, float* __restrict__ out) {
    size_t g = (size_t)blockIdx.x * 256 + threadIdx.x;
    out[g] = h[g];
}

// ---------------------------------------------------------------------------
__global__ void silu_mul_kernel(unsigned short* __restrict__ hid1,
                                const unsigned short* __restrict__ hid2) {
    size_t g = ((size_t)blockIdx.x * 256 + threadIdx.x) * 8;
    s16x8 a = *(s16x8*)(hid1 + g);
    s16x8 b = *(const s16x8*)(hid2 + g);
    s16x8 o;
#pragma unroll
    for (int i = 0; i < 8; i++) {
        float f1 = bf2f((unsigned short)a[i]);
        float f2 = bf2f((unsigned short)b[i]);
        float sv = f1 / (1.f + expf(-f1));
        o[i] = (short)f2bf(sv * f2);
    }
    *(s16x8*)(hid1 + g) = o;
}

// ---------------------------------------------------------------------------
extern "C" void kernel_launch(void* const* d_in, const int* in_sizes, int n_in,
                              void* d_out, int out_size, void* d_ws, size_t ws_size,
                              hipStream_t stream) {
    const float* x           = (const float*)d_in[0];
    const float* attn_norm_w = (const float*)d_in[1];
    const float* wq          = (const float*)d_in[2];
    const float* wk          = (const float*)d_in[3];
    const float* wv          = (const float*)d_in[4];
    const float* wo          = (const float*)d_in[5];
    const float* mlp_norm_w  = (const float*)d_in[6];
    const float* router_w    = (const float*)d_in[7];
    const float* w1          = (const float*)d_in[8];
    const float* w2          = (const float*)d_in[9];
    const float* w3          = (const float*)d_in[10];
    float* out = (float*)d_out;
    float* ws  = (float*)d_ws;

    const size_t MTC = (size_t)TT * CC;       // 2M
    size_t o = 0;
    float* xn   = ws + o; o += MTC;
    float* q    = ws + o; o += MTC;
    float* kbuf = ws + o; o += MTC;
    float* vbuf = ws + o; o += MTC;
    float* y    = ws + o; o += MTC;
    float* h    = ws + o; o += MTC;
    float* hn   = ws + o; o += MTC;
    unsigned short* hnb  = (unsigned short*)(ws + o); o += MTC / 2;
    unsigned short* hid1 = (unsigned short*)(ws + o); o += (size_t)ROWCAP * HIDD / 2;
    unsigned short* hid2 = (unsigned short*)(ws + o); o += (size_t)ROWCAP * HIDD / 2;
    float* topp = ws + o; o += TT * 2;
    float* roww = ws + o; o += ROWCAP;
    float* psum = ws + o; o += EE;
    float* argc = ws + o; o += EE;
    int* topi   = (int*)(ws + o);
    int* cnt    = topi + TT * 2;
    int* offs   = cnt + EE;
    int* cursor = offs + EE + 1;
    int* rowtok = cursor + EE;

    init_kernel<<<(ROWCAP + 255) / 256, 256, 0, stream>>>(rowtok, cnt, psum, argc);
    rmsnorm_kernel<<<TT, 256, 0, stream>>>(x, attn_norm_w, xn, nullptr);

    // fused QKV, near-fp32 (split-bf16 4-term MFMA)
    gemm_precise<0><<<dim3(TT / 128, 24), 256, 0, stream>>>(
        xn, wq, wk, wv, q, kbuf, vbuf, nullptr, CC);

    rope_kernel<<<TT * NHH / 2, 64, 0, stream>>>(q);
    rope_kernel<<<TT * NHH / 2, 64, 0, stream>>>(kbuf);

    // flash attention (near-fp32 MFMA), 16 heads x 32 q-tiles, balanced 1-D grid
    attn_flash<<<dim3(NHH * (TT / 64)), 256, 0, stream>>>(q, kbuf, vbuf, y);

    // proj + residual: h = x + y @ wo, near-fp32
    gemm_precise<1><<<dim3(TT / 128, CC / 128), 256, 0, stream>>>(
        y, wo, nullptr, nullptr, h, nullptr, nullptr, x, CC);

    rmsnorm_kernel<<<TT, 256, 0, stream>>>(h, mlp_norm_w, hn, hnb);

    router_kernel<<<TT, 64, 0, stream>>>(hn, router_w, topi, topp, cnt, psum, argc);
    offsets_kernel<<<1, 1, 0, stream>>>(cnt, offs, cursor, psum, argc, out);
    scatter_kernel<<<(TT * 2 + 255) / 256, 256, 0, stream>>>(topi, topp, cursor, rowtok, roww);
    copy_kernel<<<TT * CC / 256, 256, 0, stream>>>(h, out);

    // MoE up (fast bf16): h1 -> hid1, h2 -> hid2
    gemm_bf16<2><<<dim3(ROWCAP / 128, HIDD / 128), 256, 0, stream>>>(
        hnb, w1, nullptr, hid1, offs, rowtok, nullptr, CC, HIDD);
    gemm_bf16<2><<<dim3(ROWCAP / 128, HIDD / 128), 256, 0, stream>>>(
        hnb, w2, nullptr, hid2, offs, rowtok, nullptr, CC, HIDD);
    silu_mul_kernel<<<(size_t)ROWCAP * HIDD / 2048, 256, 0, stream>>>(hid1, hid2);

    // MoE down + weighted scatter-add into out
    gemm_bf16<3><<<dim3(ROWCAP / 128, CC / 128), 256, 0, stream>>>(
        hid1, w3, out, nullptr, offs, rowtok, roww, HIDD, CC);
}